// Round 1
// baseline (452.037 us; speedup 1.0000x reference)
//
#include <hip/hip_runtime.h>
#include <hip/hip_bf16.h>

#define N_NODES 50000
#define N_EDGES 600000
#define DIM 128

static constexpr size_t alignup(size_t x) { return (x + 255) & ~size_t(255); }
static constexpr size_t OFF_FLAG = 0;
static constexpr size_t OFF_CNT  = 256;
static constexpr size_t OFF_OFFS = alignup(OFF_CNT + sizeof(unsigned) * N_NODES);
static constexpr size_t OFF_CUR  = alignup(OFF_OFFS + sizeof(unsigned) * (N_NODES + 1));
static constexpr size_t OFF_COL  = alignup(OFF_CUR + sizeof(unsigned) * N_NODES);
static constexpr size_t OFF_AGG  = alignup(OFF_COL + sizeof(int) * N_EDGES);
static constexpr size_t OFF_H1   = alignup(OFF_AGG + sizeof(float) * N_NODES * DIM);
static constexpr size_t OFF_H2   = alignup(OFF_H1 + sizeof(float) * N_NODES * DIM);

// ---- edge dtype detection: int64 arrays have zero high words at odd indices ----
__global__ void detect_k(const int* __restrict__ ei, unsigned* __restrict__ flag) {
    int g = blockIdx.x * blockDim.x + threadIdx.x;
    if (g < 1024) {
        unsigned v = (unsigned)ei[2 * g + 1];
        if (v) atomicOr(flag, 1u);   // nonzero odd word => int32 layout
    }
}

// flag != 0 : int32 layout  (src = ei[e],        dst = ei[E+e])
// flag == 0 : int64 layout  (src = ei[2e],       dst = ei[2(E+e)])
__global__ void count_k(const int* __restrict__ ei, const unsigned* __restrict__ flag,
                        unsigned* __restrict__ cnt) {
    int e = blockIdx.x * 256 + threadIdx.x;
    if (e >= N_EDGES) return;
    int d = (*flag) ? ei[N_EDGES + e] : ei[2 * (N_EDGES + e)];
    atomicAdd(&cnt[d], 1u);
}

__global__ __launch_bounds__(1024) void scan_k(const unsigned* __restrict__ cnt,
                                               unsigned* __restrict__ offs,
                                               unsigned* __restrict__ cur) {
    __shared__ unsigned sums[1024];
    const int CH = (N_NODES + 1023) / 1024;   // 49
    int t = threadIdx.x;
    int lo = t * CH;
    int hi = min(lo + CH, N_NODES);
    unsigned s = 0;
    for (int i = lo; i < hi; ++i) s += cnt[i];
    sums[t] = s;
    __syncthreads();
    for (int d = 1; d < 1024; d <<= 1) {
        unsigned v = (t >= d) ? sums[t - d] : 0u;
        __syncthreads();
        sums[t] += v;
        __syncthreads();
    }
    unsigned run = (t == 0) ? 0u : sums[t - 1];
    for (int i = lo; i < hi; ++i) {
        offs[i] = run;
        cur[i]  = run;
        run += cnt[i];
    }
    if (t == 1023) offs[N_NODES] = sums[1023];
}

__global__ void fill_k(const int* __restrict__ ei, const unsigned* __restrict__ flag,
                       unsigned* __restrict__ cur, int* __restrict__ col) {
    int e = blockIdx.x * 256 + threadIdx.x;
    if (e >= N_EDGES) return;
    int s, d;
    if (*flag) { s = ei[e];     d = ei[N_EDGES + e]; }
    else       { s = ei[2 * e]; d = ei[2 * (N_EDGES + e)]; }
    unsigned pos = atomicAdd(&cur[d], 1u);
    col[pos] = s;
}

// mean-aggregate: 8 nodes/block, 32 lanes/node, float4 per lane
__global__ __launch_bounds__(256) void agg_k(const float* __restrict__ h,
                                             const unsigned* __restrict__ offs,
                                             const unsigned* __restrict__ cnt,
                                             const int* __restrict__ col,
                                             float* __restrict__ aggm) {
    int g    = threadIdx.x >> 5;
    int lane = threadIdx.x & 31;
    int node = blockIdx.x * 8 + g;
    if (node >= N_NODES) return;
    unsigned e0 = offs[node], e1 = offs[node + 1];
    float4 acc = {0.f, 0.f, 0.f, 0.f};
    for (unsigned e = e0; e < e1; ++e) {
        int s = col[e];
        const float4 v = *reinterpret_cast<const float4*>(&h[(size_t)s * DIM + lane * 4]);
        acc.x += v.x; acc.y += v.y; acc.z += v.z; acc.w += v.w;
    }
    float inv = 1.0f / fmaxf((float)cnt[node], 1.0f);
    acc.x *= inv; acc.y *= inv; acc.z *= inv; acc.w *= inv;
    *reinterpret_cast<float4*>(&aggm[(size_t)node * DIM + lane * 4]) = acc;
}

// out = [relu]( aggm @ Wl^T + b + hin @ Wr^T ),  M=50000, N=128, K=2*128
template <bool RELU>
__global__ __launch_bounds__(256) void xform_k(const float* __restrict__ aggm,
                                               const float* __restrict__ hin,
                                               const float* __restrict__ Wl,
                                               const float* __restrict__ Wr,
                                               const float* __restrict__ bias,
                                               float* __restrict__ hout) {
    __shared__ float As[32][68];    // [k][m], pad 68: 2-way-free banking, float4-aligned
    __shared__ float Ws[32][128];   // [k][o]
    const int t  = threadIdx.x;
    const int m0 = blockIdx.x * 64;

    const int tm = t & 15;          // node micro-row group: nodes m0 + tm*4 .. +3
    const int o0 = (t >> 4) * 8;    // 8 output features

    const int ma  = t >> 2;         // A-load: row 0..63
    const int ka  = (t & 3) * 8;    // A-load: 8 consecutive k
    const int ow  = t >> 1;         // W-load: o row 0..127
    const int kw0 = (t & 1) * 16;   // W-load: 16 consecutive k

    float acc[4][8];
#pragma unroll
    for (int i = 0; i < 4; ++i)
#pragma unroll
        for (int j = 0; j < 8; ++j) acc[i][j] = 0.f;

    for (int kc = 0; kc < 8; ++kc) {
        const float* Asrc = (kc < 4) ? aggm : hin;
        const float* Wsrc = (kc < 4) ? Wl : Wr;
        const int kbase = (kc & 3) * 32;

        __syncthreads();
        {   // A tile -> LDS (transposed)
            float v[8];
            const int node = m0 + ma;
            if (node < N_NODES) {
                const float4 v0 = *reinterpret_cast<const float4*>(&Asrc[(size_t)node * DIM + kbase + ka]);
                const float4 v1 = *reinterpret_cast<const float4*>(&Asrc[(size_t)node * DIM + kbase + ka + 4]);
                v[0] = v0.x; v[1] = v0.y; v[2] = v0.z; v[3] = v0.w;
                v[4] = v1.x; v[5] = v1.y; v[6] = v1.z; v[7] = v1.w;
            } else {
#pragma unroll
                for (int i = 0; i < 8; ++i) v[i] = 0.f;
            }
#pragma unroll
            for (int i = 0; i < 8; ++i) As[ka + i][ma] = v[i];
        }
        {   // W chunk -> LDS (transposed)
            const float4 w0 = *reinterpret_cast<const float4*>(&Wsrc[(size_t)ow * DIM + kbase + kw0]);
            const float4 w1 = *reinterpret_cast<const float4*>(&Wsrc[(size_t)ow * DIM + kbase + kw0 + 4]);
            const float4 w2 = *reinterpret_cast<const float4*>(&Wsrc[(size_t)ow * DIM + kbase + kw0 + 8]);
            const float4 w3 = *reinterpret_cast<const float4*>(&Wsrc[(size_t)ow * DIM + kbase + kw0 + 12]);
            const float w[16] = {w0.x, w0.y, w0.z, w0.w, w1.x, w1.y, w1.z, w1.w,
                                 w2.x, w2.y, w2.z, w2.w, w3.x, w3.y, w3.z, w3.w};
#pragma unroll
            for (int i = 0; i < 16; ++i) Ws[kw0 + i][ow] = w[i];
        }
        __syncthreads();

#pragma unroll 8
        for (int k = 0; k < 32; ++k) {
            const float4 a  = *reinterpret_cast<const float4*>(&As[k][tm * 4]);
            const float4 wA = *reinterpret_cast<const float4*>(&Ws[k][o0]);
            const float4 wB = *reinterpret_cast<const float4*>(&Ws[k][o0 + 4]);
            const float av[4] = {a.x, a.y, a.z, a.w};
            const float wv[8] = {wA.x, wA.y, wA.z, wA.w, wB.x, wB.y, wB.z, wB.w};
#pragma unroll
            for (int i = 0; i < 4; ++i)
#pragma unroll
                for (int j = 0; j < 8; ++j)
                    acc[i][j] = fmaf(av[i], wv[j], acc[i][j]);
        }
    }

    float bj[8];
#pragma unroll
    for (int j = 0; j < 8; ++j) bj[j] = bias[o0 + j];
#pragma unroll
    for (int i = 0; i < 4; ++i) {
        const int node = m0 + tm * 4 + i;
        if (node < N_NODES) {
            float r[8];
#pragma unroll
            for (int j = 0; j < 8; ++j) {
                r[j] = acc[i][j] + bj[j];
                if (RELU) r[j] = fmaxf(r[j], 0.f);
            }
            float4 r0 = {r[0], r[1], r[2], r[3]};
            float4 r1 = {r[4], r[5], r[6], r[7]};
            *reinterpret_cast<float4*>(&hout[(size_t)node * DIM + o0])     = r0;
            *reinterpret_cast<float4*>(&hout[(size_t)node * DIM + o0 + 4]) = r1;
        }
    }
}

// final layer: OUT_DIM=2
__global__ __launch_bounds__(256) void out2_k(const float* __restrict__ aggm,
                                              const float* __restrict__ hin,
                                              const float* __restrict__ Wl,
                                              const float* __restrict__ Wr,
                                              const float* __restrict__ bias,
                                              float* __restrict__ out) {
    __shared__ float wl[2][128], wr[2][128];
    int t = threadIdx.x;
    wl[t >> 7][t & 127] = Wl[t];
    wr[t >> 7][t & 127] = Wr[t];
    __syncthreads();
    int n = blockIdx.x * 256 + t;
    if (n >= N_NODES) return;
    const float4* pa = reinterpret_cast<const float4*>(&aggm[(size_t)n * DIM]);
    const float4* ph = reinterpret_cast<const float4*>(&hin[(size_t)n * DIM]);
    float a0 = 0.f, a1 = 0.f;
#pragma unroll
    for (int k4 = 0; k4 < 32; ++k4) {
        const float4 va = pa[k4];
        const float4 vh = ph[k4];
        const int k = k4 * 4;
        a0 += va.x * wl[0][k] + va.y * wl[0][k + 1] + va.z * wl[0][k + 2] + va.w * wl[0][k + 3]
            + vh.x * wr[0][k] + vh.y * wr[0][k + 1] + vh.z * wr[0][k + 2] + vh.w * wr[0][k + 3];
        a1 += va.x * wl[1][k] + va.y * wl[1][k + 1] + va.z * wl[1][k + 2] + va.w * wl[1][k + 3]
            + vh.x * wr[1][k] + vh.y * wr[1][k + 1] + vh.z * wr[1][k + 2] + vh.w * wr[1][k + 3];
    }
    out[(size_t)n * 2 + 0] = a0 + bias[0];
    out[(size_t)n * 2 + 1] = a1 + bias[1];
}

extern "C" void kernel_launch(void* const* d_in, const int* in_sizes, int n_in,
                              void* d_out, int out_size, void* d_ws, size_t ws_size,
                              hipStream_t stream) {
    const float* x   = (const float*)d_in[0];
    const int*   ei  = (const int*)d_in[1];
    const float* Wl0 = (const float*)d_in[2];
    const float* Wr0 = (const float*)d_in[3];
    const float* b0  = (const float*)d_in[4];
    const float* Wl1 = (const float*)d_in[5];
    const float* Wr1 = (const float*)d_in[6];
    const float* b1  = (const float*)d_in[7];
    const float* Wl2 = (const float*)d_in[8];
    const float* Wr2 = (const float*)d_in[9];
    const float* b2  = (const float*)d_in[10];

    char* ws = (char*)d_ws;
    unsigned* flag = (unsigned*)(ws + OFF_FLAG);
    unsigned* cnt  = (unsigned*)(ws + OFF_CNT);
    unsigned* offs = (unsigned*)(ws + OFF_OFFS);
    unsigned* cur  = (unsigned*)(ws + OFF_CUR);
    int*      col  = (int*)(ws + OFF_COL);
    float*    aggm = (float*)(ws + OFF_AGG);
    float*    h1   = (float*)(ws + OFF_H1);
    float*    h2   = (float*)(ws + OFF_H2);
    float*    out  = (float*)d_out;

    hipMemsetAsync(ws, 0, OFF_CNT + sizeof(unsigned) * N_NODES, stream);

    detect_k<<<4, 256, 0, stream>>>(ei, flag);
    count_k<<<(N_EDGES + 255) / 256, 256, 0, stream>>>(ei, flag, cnt);
    scan_k<<<1, 1024, 0, stream>>>(cnt, offs, cur);
    fill_k<<<(N_EDGES + 255) / 256, 256, 0, stream>>>(ei, flag, cur, col);

    // layer 0: x -> h1
    agg_k<<<(N_NODES + 7) / 8, 256, 0, stream>>>(x, offs, cnt, col, aggm);
    xform_k<true><<<(N_NODES + 63) / 64, 256, 0, stream>>>(aggm, x, Wl0, Wr0, b0, h1);
    // layer 1: h1 -> h2
    agg_k<<<(N_NODES + 7) / 8, 256, 0, stream>>>(h1, offs, cnt, col, aggm);
    xform_k<true><<<(N_NODES + 63) / 64, 256, 0, stream>>>(aggm, h1, Wl1, Wr1, b1, h2);
    // layer 2: h2 -> out
    agg_k<<<(N_NODES + 7) / 8, 256, 0, stream>>>(h2, offs, cnt, col, aggm);
    out2_k<<<(N_NODES + 255) / 256, 256, 0, stream>>>(aggm, h2, Wl2, Wr2, b2, out);
}

// Round 2
// 357.699 us; speedup vs baseline: 1.2637x; 1.2637x over previous
//
#include <hip/hip_runtime.h>
#include <hip/hip_bf16.h>

#define N_NODES 50000
#define N_EDGES 600000
#define DIM 128

#define SCAN_CHUNK 2048
#define N_CHUNKS ((N_NODES + SCAN_CHUNK - 1) / SCAN_CHUNK)   // 25

static constexpr size_t alignup(size_t x) { return (x + 255) & ~size_t(255); }
static constexpr size_t OFF_FLAG = 0;
static constexpr size_t OFF_TOT  = 256;                       // chunk totals (25)
static constexpr size_t OFF_CNT  = alignup(OFF_TOT + sizeof(unsigned) * N_CHUNKS);
static constexpr size_t OFF_OFFS = alignup(OFF_CNT + sizeof(unsigned) * N_NODES);
static constexpr size_t OFF_CUR  = alignup(OFF_OFFS + sizeof(unsigned) * (N_NODES + 1));
static constexpr size_t OFF_COL  = alignup(OFF_CUR + sizeof(unsigned) * N_NODES);
static constexpr size_t OFF_AGG  = alignup(OFF_COL + sizeof(int) * N_EDGES);
static constexpr size_t OFF_H1   = alignup(OFF_AGG + sizeof(float) * N_NODES * DIM);
static constexpr size_t OFF_H2   = alignup(OFF_H1 + sizeof(float) * N_NODES * DIM);

// ---- edge dtype detection: int64 arrays have zero high words at odd indices ----
__global__ void detect_k(const int* __restrict__ ei, unsigned* __restrict__ flag) {
    int g = blockIdx.x * blockDim.x + threadIdx.x;
    if (g < 1024) {
        unsigned v = (unsigned)ei[2 * g + 1];
        if (v) atomicOr(flag, 1u);   // nonzero odd word => int32 layout
    }
}

// flag != 0 : int32 layout  (src = ei[e],        dst = ei[E+e])
// flag == 0 : int64 layout  (src = ei[2e],       dst = ei[2(E+e)])
__global__ void count_k(const int* __restrict__ ei, const unsigned* __restrict__ flag,
                        unsigned* __restrict__ cnt) {
    int e = blockIdx.x * 256 + threadIdx.x;
    if (e >= N_EDGES) return;
    int d = (*flag) ? ei[N_EDGES + e] : ei[2 * (N_EDGES + e)];
    atomicAdd(&cnt[d], 1u);
}

// ---- 3-phase chunked exclusive scan (replaces 112us single-block scan) ----
__global__ __launch_bounds__(256) void scanA_k(const unsigned* __restrict__ cnt,
                                               unsigned* __restrict__ totals) {
    __shared__ unsigned red[256];
    const int b = blockIdx.x, t = threadIdx.x;
    const int base = b * SCAN_CHUNK + t * 8;
    unsigned s = 0;
#pragma unroll
    for (int i = 0; i < 8; ++i) {
        int idx = base + i;
        if (idx < N_NODES) s += cnt[idx];
    }
    red[t] = s;
    __syncthreads();
    for (int d = 128; d > 0; d >>= 1) {
        if (t < d) red[t] += red[t + d];
        __syncthreads();
    }
    if (t == 0) totals[b] = red[0];
}

__global__ void scanB_k(unsigned* __restrict__ totals) {   // launch 64 threads
    int t = threadIdx.x;
    unsigned orig = (t < N_CHUNKS) ? totals[t] : 0u;
    unsigned v = orig;
    for (int d = 1; d < 64; d <<= 1) {
        unsigned n = __shfl_up(v, d);
        if (t >= d) v += n;
    }
    if (t < N_CHUNKS) totals[t] = v - orig;   // exclusive
}

__global__ __launch_bounds__(256) void scanC_k(const unsigned* __restrict__ cnt,
                                               const unsigned* __restrict__ totals,
                                               unsigned* __restrict__ offs,
                                               unsigned* __restrict__ cur) {
    __shared__ unsigned tsum[256];
    const int b = blockIdx.x, t = threadIdx.x;
    const int base = b * SCAN_CHUNK + t * 8;
    unsigned v[8];
    unsigned s = 0;
#pragma unroll
    for (int i = 0; i < 8; ++i) {
        int idx = base + i;
        v[i] = (idx < N_NODES) ? cnt[idx] : 0u;
        s += v[i];
    }
    tsum[t] = s;
    __syncthreads();
    for (int d = 1; d < 256; d <<= 1) {
        unsigned nv = (t >= d) ? tsum[t - d] : 0u;
        __syncthreads();
        tsum[t] += nv;
        __syncthreads();
    }
    unsigned run = tsum[t] - s + totals[b];   // exclusive across block + chunk base
    for (int i = 0; i < 8; ++i) {
        int idx = base + i;
        if (idx < N_NODES) {
            offs[idx] = run;
            cur[idx]  = run;
            run += v[i];
            if (idx == N_NODES - 1) offs[N_NODES] = run;
        }
    }
}

__global__ void fill_k(const int* __restrict__ ei, const unsigned* __restrict__ flag,
                       unsigned* __restrict__ cur, int* __restrict__ col) {
    int e = blockIdx.x * 256 + threadIdx.x;
    if (e >= N_EDGES) return;
    int s, d;
    if (*flag) { s = ei[e];     d = ei[N_EDGES + e]; }
    else       { s = ei[2 * e]; d = ei[2 * (N_EDGES + e)]; }
    unsigned pos = atomicAdd(&cur[d], 1u);
    col[pos] = s;
}

// mean-aggregate: 8 nodes/block, 32 lanes/node, float4 per lane
__global__ __launch_bounds__(256) void agg_k(const float* __restrict__ h,
                                             const unsigned* __restrict__ offs,
                                             const unsigned* __restrict__ cnt,
                                             const int* __restrict__ col,
                                             float* __restrict__ aggm) {
    int g    = threadIdx.x >> 5;
    int lane = threadIdx.x & 31;
    int node = blockIdx.x * 8 + g;
    if (node >= N_NODES) return;
    unsigned e0 = offs[node], e1 = offs[node + 1];
    float4 acc = {0.f, 0.f, 0.f, 0.f};
    for (unsigned e = e0; e < e1; ++e) {
        int s = col[e];
        const float4 v = *reinterpret_cast<const float4*>(&h[(size_t)s * DIM + lane * 4]);
        acc.x += v.x; acc.y += v.y; acc.z += v.z; acc.w += v.w;
    }
    float inv = 1.0f / fmaxf((float)cnt[node], 1.0f);
    acc.x *= inv; acc.y *= inv; acc.z *= inv; acc.w *= inv;
    *reinterpret_cast<float4*>(&aggm[(size_t)node * DIM + lane * 4]) = acc;
}

// out = [relu]( aggm @ Wl^T + b + hin @ Wr^T ),  M=50000, N=128, K=2*128
template <bool RELU>
__global__ __launch_bounds__(256) void xform_k(const float* __restrict__ aggm,
                                               const float* __restrict__ hin,
                                               const float* __restrict__ Wl,
                                               const float* __restrict__ Wr,
                                               const float* __restrict__ bias,
                                               float* __restrict__ hout) {
    __shared__ float As[32][68];    // [k][m], pad 68: 2-way-free banking, float4-aligned
    __shared__ float Ws[32][128];   // [k][o]
    const int t  = threadIdx.x;
    const int m0 = blockIdx.x * 64;

    const int tm = t & 15;          // node micro-row group: nodes m0 + tm*4 .. +3
    const int o0 = (t >> 4) * 8;    // 8 output features

    const int ma  = t >> 2;         // A-load: row 0..63
    const int ka  = (t & 3) * 8;    // A-load: 8 consecutive k
    const int ow  = t >> 1;         // W-load: o row 0..127
    const int kw0 = (t & 1) * 16;   // W-load: 16 consecutive k

    float acc[4][8];
#pragma unroll
    for (int i = 0; i < 4; ++i)
#pragma unroll
        for (int j = 0; j < 8; ++j) acc[i][j] = 0.f;

    for (int kc = 0; kc < 8; ++kc) {
        const float* Asrc = (kc < 4) ? aggm : hin;
        const float* Wsrc = (kc < 4) ? Wl : Wr;
        const int kbase = (kc & 3) * 32;

        __syncthreads();
        {   // A tile -> LDS (transposed)
            float v[8];
            const int node = m0 + ma;
            if (node < N_NODES) {
                const float4 v0 = *reinterpret_cast<const float4*>(&Asrc[(size_t)node * DIM + kbase + ka]);
                const float4 v1 = *reinterpret_cast<const float4*>(&Asrc[(size_t)node * DIM + kbase + ka + 4]);
                v[0] = v0.x; v[1] = v0.y; v[2] = v0.z; v[3] = v0.w;
                v[4] = v1.x; v[5] = v1.y; v[6] = v1.z; v[7] = v1.w;
            } else {
#pragma unroll
                for (int i = 0; i < 8; ++i) v[i] = 0.f;
            }
#pragma unroll
            for (int i = 0; i < 8; ++i) As[ka + i][ma] = v[i];
        }
        {   // W chunk -> LDS (transposed)
            const float4 w0 = *reinterpret_cast<const float4*>(&Wsrc[(size_t)ow * DIM + kbase + kw0]);
            const float4 w1 = *reinterpret_cast<const float4*>(&Wsrc[(size_t)ow * DIM + kbase + kw0 + 4]);
            const float4 w2 = *reinterpret_cast<const float4*>(&Wsrc[(size_t)ow * DIM + kbase + kw0 + 8]);
            const float4 w3 = *reinterpret_cast<const float4*>(&Wsrc[(size_t)ow * DIM + kbase + kw0 + 12]);
            const float w[16] = {w0.x, w0.y, w0.z, w0.w, w1.x, w1.y, w1.z, w1.w,
                                 w2.x, w2.y, w2.z, w2.w, w3.x, w3.y, w3.z, w3.w};
#pragma unroll
            for (int i = 0; i < 16; ++i) Ws[kw0 + i][ow] = w[i];
        }
        __syncthreads();

#pragma unroll 8
        for (int k = 0; k < 32; ++k) {
            const float4 a  = *reinterpret_cast<const float4*>(&As[k][tm * 4]);
            const float4 wA = *reinterpret_cast<const float4*>(&Ws[k][o0]);
            const float4 wB = *reinterpret_cast<const float4*>(&Ws[k][o0 + 4]);
            const float av[4] = {a.x, a.y, a.z, a.w};
            const float wv[8] = {wA.x, wA.y, wA.z, wA.w, wB.x, wB.y, wB.z, wB.w};
#pragma unroll
            for (int i = 0; i < 4; ++i)
#pragma unroll
                for (int j = 0; j < 8; ++j)
                    acc[i][j] = fmaf(av[i], wv[j], acc[i][j]);
        }
    }

    float bj[8];
#pragma unroll
    for (int j = 0; j < 8; ++j) bj[j] = bias[o0 + j];
#pragma unroll
    for (int i = 0; i < 4; ++i) {
        const int node = m0 + tm * 4 + i;
        if (node < N_NODES) {
            float r[8];
#pragma unroll
            for (int j = 0; j < 8; ++j) {
                r[j] = acc[i][j] + bj[j];
                if (RELU) r[j] = fmaxf(r[j], 0.f);
            }
            float4 r0 = {r[0], r[1], r[2], r[3]};
            float4 r1 = {r[4], r[5], r[6], r[7]};
            *reinterpret_cast<float4*>(&hout[(size_t)node * DIM + o0])     = r0;
            *reinterpret_cast<float4*>(&hout[(size_t)node * DIM + o0 + 4]) = r1;
        }
    }
}

// final layer: OUT_DIM=2
__global__ __launch_bounds__(256) void out2_k(const float* __restrict__ aggm,
                                              const float* __restrict__ hin,
                                              const float* __restrict__ Wl,
                                              const float* __restrict__ Wr,
                                              const float* __restrict__ bias,
                                              float* __restrict__ out) {
    __shared__ float wl[2][128], wr[2][128];
    int t = threadIdx.x;
    wl[t >> 7][t & 127] = Wl[t];
    wr[t >> 7][t & 127] = Wr[t];
    __syncthreads();
    int n = blockIdx.x * 256 + t;
    if (n >= N_NODES) return;
    const float4* pa = reinterpret_cast<const float4*>(&aggm[(size_t)n * DIM]);
    const float4* ph = reinterpret_cast<const float4*>(&hin[(size_t)n * DIM]);
    float a0 = 0.f, a1 = 0.f;
#pragma unroll
    for (int k4 = 0; k4 < 32; ++k4) {
        const float4 va = pa[k4];
        const float4 vh = ph[k4];
        const int k = k4 * 4;
        a0 += va.x * wl[0][k] + va.y * wl[0][k + 1] + va.z * wl[0][k + 2] + va.w * wl[0][k + 3]
            + vh.x * wr[0][k] + vh.y * wr[0][k + 1] + vh.z * wr[0][k + 2] + vh.w * wr[0][k + 3];
        a1 += va.x * wl[1][k] + va.y * wl[1][k + 1] + va.z * wl[1][k + 2] + va.w * wl[1][k + 3]
            + vh.x * wr[1][k] + vh.y * wr[1][k + 1] + vh.z * wr[1][k + 2] + vh.w * wr[1][k + 3];
    }
    out[(size_t)n * 2 + 0] = a0 + bias[0];
    out[(size_t)n * 2 + 1] = a1 + bias[1];
}

extern "C" void kernel_launch(void* const* d_in, const int* in_sizes, int n_in,
                              void* d_out, int out_size, void* d_ws, size_t ws_size,
                              hipStream_t stream) {
    const float* x   = (const float*)d_in[0];
    const int*   ei  = (const int*)d_in[1];
    const float* Wl0 = (const float*)d_in[2];
    const float* Wr0 = (const float*)d_in[3];
    const float* b0  = (const float*)d_in[4];
    const float* Wl1 = (const float*)d_in[5];
    const float* Wr1 = (const float*)d_in[6];
    const float* b1  = (const float*)d_in[7];
    const float* Wl2 = (const float*)d_in[8];
    const float* Wr2 = (const float*)d_in[9];
    const float* b2  = (const float*)d_in[10];

    char* ws = (char*)d_ws;
    unsigned* flag = (unsigned*)(ws + OFF_FLAG);
    unsigned* tot  = (unsigned*)(ws + OFF_TOT);
    unsigned* cnt  = (unsigned*)(ws + OFF_CNT);
    unsigned* offs = (unsigned*)(ws + OFF_OFFS);
    unsigned* cur  = (unsigned*)(ws + OFF_CUR);
    int*      col  = (int*)(ws + OFF_COL);
    float*    aggm = (float*)(ws + OFF_AGG);
    float*    h1   = (float*)(ws + OFF_H1);
    float*    h2   = (float*)(ws + OFF_H2);
    float*    out  = (float*)d_out;

    hipMemsetAsync(ws, 0, OFF_CNT + sizeof(unsigned) * N_NODES, stream);

    detect_k<<<4, 256, 0, stream>>>(ei, flag);
    count_k<<<(N_EDGES + 255) / 256, 256, 0, stream>>>(ei, flag, cnt);
    scanA_k<<<N_CHUNKS, 256, 0, stream>>>(cnt, tot);
    scanB_k<<<1, 64, 0, stream>>>(tot);
    scanC_k<<<N_CHUNKS, 256, 0, stream>>>(cnt, tot, offs, cur);
    fill_k<<<(N_EDGES + 255) / 256, 256, 0, stream>>>(ei, flag, cur, col);

    // layer 0: x -> h1
    agg_k<<<(N_NODES + 7) / 8, 256, 0, stream>>>(x, offs, cnt, col, aggm);
    xform_k<true><<<(N_NODES + 63) / 64, 256, 0, stream>>>(aggm, x, Wl0, Wr0, b0, h1);
    // layer 1: h1 -> h2
    agg_k<<<(N_NODES + 7) / 8, 256, 0, stream>>>(h1, offs, cnt, col, aggm);
    xform_k<true><<<(N_NODES + 63) / 64, 256, 0, stream>>>(aggm, h1, Wl1, Wr1, b1, h2);
    // layer 2: h2 -> out
    agg_k<<<(N_NODES + 7) / 8, 256, 0, stream>>>(h2, offs, cnt, col, aggm);
    out2_k<<<(N_NODES + 255) / 256, 256, 0, stream>>>(aggm, h2, Wl2, Wr2, b2, out);
}

// Round 3
// 277.114 us; speedup vs baseline: 1.6312x; 1.2908x over previous
//
#include <hip/hip_runtime.h>
#include <hip/hip_bf16.h>

#define N_NODES 50000
#define N_EDGES 600000
#define DIM 128

#define SCAN_CHUNK 2048
#define N_CHUNKS ((N_NODES + SCAN_CHUNK - 1) / SCAN_CHUNK)   // 25

typedef short bf16x8 __attribute__((ext_vector_type(8)));
typedef float f32x4 __attribute__((ext_vector_type(4)));

__device__ __forceinline__ ushort f2b(float f) {
    __hip_bfloat16 h = __float2bfloat16(f);
    return *reinterpret_cast<ushort*>(&h);
}
__device__ __forceinline__ float b2f_lo(unsigned u) { return __uint_as_float(u << 16); }
__device__ __forceinline__ float b2f_hi(unsigned u) { return __uint_as_float(u & 0xffff0000u); }

static constexpr size_t alignup(size_t x) { return (x + 255) & ~size_t(255); }
static constexpr size_t OFF_FLAG = 0;
static constexpr size_t OFF_TOT  = 256;
static constexpr size_t OFF_CNT  = alignup(OFF_TOT + sizeof(unsigned) * N_CHUNKS);
static constexpr size_t OFF_OFFS = alignup(OFF_CNT + sizeof(unsigned) * N_NODES);
static constexpr size_t OFF_CUR  = alignup(OFF_OFFS + sizeof(unsigned) * (N_NODES + 1));
static constexpr size_t OFF_COL  = alignup(OFF_CUR + sizeof(unsigned) * N_NODES);
static constexpr size_t OFF_XBF  = alignup(OFF_COL + sizeof(int) * N_EDGES);
static constexpr size_t OFF_AGG  = alignup(OFF_XBF + sizeof(ushort) * N_NODES * DIM);
static constexpr size_t OFF_H1   = alignup(OFF_AGG + sizeof(ushort) * N_NODES * DIM);
static constexpr size_t OFF_H2   = alignup(OFF_H1 + sizeof(ushort) * N_NODES * DIM);
static constexpr size_t OFF_WL0  = alignup(OFF_H2 + sizeof(ushort) * N_NODES * DIM);
static constexpr size_t OFF_WR0  = alignup(OFF_WL0 + sizeof(ushort) * DIM * DIM);
static constexpr size_t OFF_WL1  = alignup(OFF_WR0 + sizeof(ushort) * DIM * DIM);
static constexpr size_t OFF_WR1  = alignup(OFF_WL1 + sizeof(ushort) * DIM * DIM);

// ---- edge dtype detection: int64 arrays have zero high words at odd indices ----
__global__ void detect_k(const int* __restrict__ ei, unsigned* __restrict__ flag) {
    int g = blockIdx.x * blockDim.x + threadIdx.x;
    if (g < 1024) {
        unsigned v = (unsigned)ei[2 * g + 1];
        if (v) atomicOr(flag, 1u);   // nonzero odd word => int32 layout
    }
}

__global__ void count_k(const int* __restrict__ ei, const unsigned* __restrict__ flag,
                        unsigned* __restrict__ cnt) {
    int e = blockIdx.x * 256 + threadIdx.x;
    if (e >= N_EDGES) return;
    int d = (*flag) ? ei[N_EDGES + e] : ei[2 * (N_EDGES + e)];
    atomicAdd(&cnt[d], 1u);
}

// ---- 3-phase chunked exclusive scan ----
__global__ __launch_bounds__(256) void scanA_k(const unsigned* __restrict__ cnt,
                                               unsigned* __restrict__ totals) {
    __shared__ unsigned red[256];
    const int b = blockIdx.x, t = threadIdx.x;
    const int base = b * SCAN_CHUNK + t * 8;
    unsigned s = 0;
#pragma unroll
    for (int i = 0; i < 8; ++i) {
        int idx = base + i;
        if (idx < N_NODES) s += cnt[idx];
    }
    red[t] = s;
    __syncthreads();
    for (int d = 128; d > 0; d >>= 1) {
        if (t < d) red[t] += red[t + d];
        __syncthreads();
    }
    if (t == 0) totals[b] = red[0];
}

__global__ void scanB_k(unsigned* __restrict__ totals) {   // 64 threads
    int t = threadIdx.x;
    unsigned orig = (t < N_CHUNKS) ? totals[t] : 0u;
    unsigned v = orig;
    for (int d = 1; d < 64; d <<= 1) {
        unsigned n = __shfl_up(v, d);
        if (t >= d) v += n;
    }
    if (t < N_CHUNKS) totals[t] = v - orig;   // exclusive
}

__global__ __launch_bounds__(256) void scanC_k(const unsigned* __restrict__ cnt,
                                               const unsigned* __restrict__ totals,
                                               unsigned* __restrict__ offs,
                                               unsigned* __restrict__ cur) {
    __shared__ unsigned tsum[256];
    const int b = blockIdx.x, t = threadIdx.x;
    const int base = b * SCAN_CHUNK + t * 8;
    unsigned v[8];
    unsigned s = 0;
#pragma unroll
    for (int i = 0; i < 8; ++i) {
        int idx = base + i;
        v[i] = (idx < N_NODES) ? cnt[idx] : 0u;
        s += v[i];
    }
    tsum[t] = s;
    __syncthreads();
    for (int d = 1; d < 256; d <<= 1) {
        unsigned nv = (t >= d) ? tsum[t - d] : 0u;
        __syncthreads();
        tsum[t] += nv;
        __syncthreads();
    }
    unsigned run = tsum[t] - s + totals[b];
    for (int i = 0; i < 8; ++i) {
        int idx = base + i;
        if (idx < N_NODES) {
            offs[idx] = run;
            cur[idx]  = run;
            run += v[i];
            if (idx == N_NODES - 1) offs[N_NODES] = run;
        }
    }
}

__global__ void fill_k(const int* __restrict__ ei, const unsigned* __restrict__ flag,
                       unsigned* __restrict__ cur, int* __restrict__ col) {
    int e = blockIdx.x * 256 + threadIdx.x;
    if (e >= N_EDGES) return;
    int s, d;
    if (*flag) { s = ei[e];     d = ei[N_EDGES + e]; }
    else       { s = ei[2 * e]; d = ei[2 * (N_EDGES + e)]; }
    unsigned pos = atomicAdd(&cur[d], 1u);
    col[pos] = s;
}

// ---- f32 -> bf16 converters ----
__global__ __launch_bounds__(256) void f2b_k(const float* __restrict__ src,
                                             ushort* __restrict__ dst, int n4) {
    int i = blockIdx.x * 256 + threadIdx.x;
    if (i >= n4) return;
    float4 v = reinterpret_cast<const float4*>(src)[i];
    ushort4 o;
    o.x = f2b(v.x); o.y = f2b(v.y); o.z = f2b(v.z); o.w = f2b(v.w);
    reinterpret_cast<ushort4*>(dst)[i] = o;
}

__global__ __launch_bounds__(256) void wconv_k(const float* __restrict__ a, const float* __restrict__ b,
                                               const float* __restrict__ c, const float* __restrict__ d,
                                               ushort* __restrict__ oa, ushort* __restrict__ ob,
                                               ushort* __restrict__ oc, ushort* __restrict__ od) {
    const int w = blockIdx.y;
    const float* src = (w == 0) ? a : (w == 1) ? b : (w == 2) ? c : d;
    ushort* dst      = (w == 0) ? oa : (w == 1) ? ob : (w == 2) ? oc : od;
    int i = blockIdx.x * 256 + threadIdx.x;          // DIM*DIM/4 = 4096 threads
    float4 v = reinterpret_cast<const float4*>(src)[i];
    ushort4 o;
    o.x = f2b(v.x); o.y = f2b(v.y); o.z = f2b(v.z); o.w = f2b(v.w);
    reinterpret_cast<ushort4*>(dst)[i] = o;
}

// ---- mean-aggregate (bf16 in, f32 accum, bf16 out): 16 nodes/block, 16 lanes/node ----
__global__ __launch_bounds__(256) void agg_k(const ushort* __restrict__ h,
                                             const unsigned* __restrict__ offs,
                                             const unsigned* __restrict__ cnt,
                                             const int* __restrict__ col,
                                             ushort* __restrict__ aggm) {
    int g    = threadIdx.x >> 4;
    int lane = threadIdx.x & 15;
    int node = blockIdx.x * 16 + g;
    if (node >= N_NODES) return;
    unsigned e0 = offs[node], e1 = offs[node + 1];
    float acc[8];
#pragma unroll
    for (int i = 0; i < 8; ++i) acc[i] = 0.f;
    for (unsigned e = e0; e < e1; ++e) {
        int s = col[e];
        uint4 v = *reinterpret_cast<const uint4*>(&h[(size_t)s * DIM + lane * 8]);
        acc[0] += b2f_lo(v.x); acc[1] += b2f_hi(v.x);
        acc[2] += b2f_lo(v.y); acc[3] += b2f_hi(v.y);
        acc[4] += b2f_lo(v.z); acc[5] += b2f_hi(v.z);
        acc[6] += b2f_lo(v.w); acc[7] += b2f_hi(v.w);
    }
    float inv = 1.0f / fmaxf((float)cnt[node], 1.0f);
    uint4 o;
    o.x = (unsigned)f2b(acc[0] * inv) | ((unsigned)f2b(acc[1] * inv) << 16);
    o.y = (unsigned)f2b(acc[2] * inv) | ((unsigned)f2b(acc[3] * inv) << 16);
    o.z = (unsigned)f2b(acc[4] * inv) | ((unsigned)f2b(acc[5] * inv) << 16);
    o.w = (unsigned)f2b(acc[6] * inv) | ((unsigned)f2b(acc[7] * inv) << 16);
    *reinterpret_cast<uint4*>(&aggm[(size_t)node * DIM + lane * 8]) = o;
}

// ---- hout = [relu]( aggm @ Wl^T + b + hin @ Wr^T ) via bf16 MFMA ----
// D = W · X^T computed per 16x16x32 MFMA: A-frag = W rows [o][k], B-frag = X rows [node][k],
// both contiguous 16B per lane. D: lane holds node=l&15, o=(l>>4)*4+reg (4 consecutive o).
template <bool RELU>
__global__ __launch_bounds__(256) void xform_mfma_k(const ushort* __restrict__ A0,   // aggm
                                                    const ushort* __restrict__ A1,   // hin (root)
                                                    const ushort* __restrict__ Wl,
                                                    const ushort* __restrict__ Wr,
                                                    const float*  __restrict__ bias,
                                                    ushort* __restrict__ hout) {
    const int t    = threadIdx.x;
    const int wave = t >> 6;
    const int l    = t & 63;
    const int l16  = l & 15;
    const int lk   = (l >> 4) * 8;                       // k offset within 32-chunk
    const int node = blockIdx.x * 64 + wave * 16 + l16;
    const bool valid = node < N_NODES;

    f32x4 acc[8];
#pragma unroll
    for (int i = 0; i < 8; ++i) acc[i] = (f32x4){0.f, 0.f, 0.f, 0.f};

    const bf16x8 zfrag = (bf16x8){0, 0, 0, 0, 0, 0, 0, 0};

#pragma unroll
    for (int ks = 0; ks < 8; ++ks) {
        const ushort* Asrc = (ks < 4) ? A0 : A1;
        const ushort* Wsrc = (ks < 4) ? Wl : Wr;
        const int kb = (ks & 3) * 32;
        const bf16x8 bfrag = valid
            ? *reinterpret_cast<const bf16x8*>(&Asrc[(size_t)node * DIM + kb + lk])
            : zfrag;
#pragma unroll
        for (int ot = 0; ot < 8; ++ot) {
            const bf16x8 afrag = *reinterpret_cast<const bf16x8*>(
                &Wsrc[(size_t)(ot * 16 + l16) * DIM + kb + lk]);
            acc[ot] = __builtin_amdgcn_mfma_f32_16x16x32_bf16(afrag, bfrag, acc[ot], 0, 0, 0);
        }
    }

    if (!valid) return;
    const int orow = (l >> 4) * 4;
#pragma unroll
    for (int ot = 0; ot < 8; ++ot) {
        const float4 b4 = *reinterpret_cast<const float4*>(&bias[ot * 16 + orow]);
        float r0 = acc[ot][0] + b4.x;
        float r1 = acc[ot][1] + b4.y;
        float r2 = acc[ot][2] + b4.z;
        float r3 = acc[ot][3] + b4.w;
        if (RELU) {
            r0 = fmaxf(r0, 0.f); r1 = fmaxf(r1, 0.f);
            r2 = fmaxf(r2, 0.f); r3 = fmaxf(r3, 0.f);
        }
        ushort4 s;
        s.x = f2b(r0); s.y = f2b(r1); s.z = f2b(r2); s.w = f2b(r3);
        *reinterpret_cast<ushort4*>(&hout[(size_t)node * DIM + ot * 16 + orow]) = s;
    }
}

// ---- final layer: OUT_DIM=2, bf16 inputs, f32 math/out ----
__global__ __launch_bounds__(256) void out2_k(const ushort* __restrict__ aggm,
                                              const ushort* __restrict__ hin,
                                              const float* __restrict__ Wl,
                                              const float* __restrict__ Wr,
                                              const float* __restrict__ bias,
                                              float* __restrict__ out) {
    __shared__ float wl[2][128], wr[2][128];
    int t = threadIdx.x;
    wl[t >> 7][t & 127] = Wl[t];
    wr[t >> 7][t & 127] = Wr[t];
    __syncthreads();
    int n = blockIdx.x * 256 + t;
    if (n >= N_NODES) return;
    const uint4* pa = reinterpret_cast<const uint4*>(&aggm[(size_t)n * DIM]);
    const uint4* ph = reinterpret_cast<const uint4*>(&hin[(size_t)n * DIM]);
    float a0 = 0.f, a1 = 0.f;
#pragma unroll
    for (int q = 0; q < 16; ++q) {
        const uint4 va = pa[q];
        const uint4 vh = ph[q];
        const int k = q * 8;
        float f;
        f = b2f_lo(va.x); a0 += f * wl[0][k + 0]; a1 += f * wl[1][k + 0];
        f = b2f_hi(va.x); a0 += f * wl[0][k + 1]; a1 += f * wl[1][k + 1];
        f = b2f_lo(va.y); a0 += f * wl[0][k + 2]; a1 += f * wl[1][k + 2];
        f = b2f_hi(va.y); a0 += f * wl[0][k + 3]; a1 += f * wl[1][k + 3];
        f = b2f_lo(va.z); a0 += f * wl[0][k + 4]; a1 += f * wl[1][k + 4];
        f = b2f_hi(va.z); a0 += f * wl[0][k + 5]; a1 += f * wl[1][k + 5];
        f = b2f_lo(va.w); a0 += f * wl[0][k + 6]; a1 += f * wl[1][k + 6];
        f = b2f_hi(va.w); a0 += f * wl[0][k + 7]; a1 += f * wl[1][k + 7];
        f = b2f_lo(vh.x); a0 += f * wr[0][k + 0]; a1 += f * wr[1][k + 0];
        f = b2f_hi(vh.x); a0 += f * wr[0][k + 1]; a1 += f * wr[1][k + 1];
        f = b2f_lo(vh.y); a0 += f * wr[0][k + 2]; a1 += f * wr[1][k + 2];
        f = b2f_hi(vh.y); a0 += f * wr[0][k + 3]; a1 += f * wr[1][k + 3];
        f = b2f_lo(vh.z); a0 += f * wr[0][k + 4]; a1 += f * wr[1][k + 4];
        f = b2f_hi(vh.z); a0 += f * wr[0][k + 5]; a1 += f * wr[1][k + 5];
        f = b2f_lo(vh.w); a0 += f * wr[0][k + 6]; a1 += f * wr[1][k + 6];
        f = b2f_hi(vh.w); a0 += f * wr[0][k + 7]; a1 += f * wr[1][k + 7];
    }
    out[(size_t)n * 2 + 0] = a0 + bias[0];
    out[(size_t)n * 2 + 1] = a1 + bias[1];
}

extern "C" void kernel_launch(void* const* d_in, const int* in_sizes, int n_in,
                              void* d_out, int out_size, void* d_ws, size_t ws_size,
                              hipStream_t stream) {
    const float* x   = (const float*)d_in[0];
    const int*   ei  = (const int*)d_in[1];
    const float* Wl0 = (const float*)d_in[2];
    const float* Wr0 = (const float*)d_in[3];
    const float* b0  = (const float*)d_in[4];
    const float* Wl1 = (const float*)d_in[5];
    const float* Wr1 = (const float*)d_in[6];
    const float* b1  = (const float*)d_in[7];
    const float* Wl2 = (const float*)d_in[8];
    const float* Wr2 = (const float*)d_in[9];
    const float* b2  = (const float*)d_in[10];

    char* ws = (char*)d_ws;
    unsigned* flag = (unsigned*)(ws + OFF_FLAG);
    unsigned* tot  = (unsigned*)(ws + OFF_TOT);
    unsigned* cnt  = (unsigned*)(ws + OFF_CNT);
    unsigned* offs = (unsigned*)(ws + OFF_OFFS);
    unsigned* cur  = (unsigned*)(ws + OFF_CUR);
    int*      col  = (int*)(ws + OFF_COL);
    ushort*   xbf  = (ushort*)(ws + OFF_XBF);
    ushort*   aggm = (ushort*)(ws + OFF_AGG);
    ushort*   h1   = (ushort*)(ws + OFF_H1);
    ushort*   h2   = (ushort*)(ws + OFF_H2);
    ushort*   wl0b = (ushort*)(ws + OFF_WL0);
    ushort*   wr0b = (ushort*)(ws + OFF_WR0);
    ushort*   wl1b = (ushort*)(ws + OFF_WL1);
    ushort*   wr1b = (ushort*)(ws + OFF_WR1);
    float*    out  = (float*)d_out;

    hipMemsetAsync(ws, 0, OFF_CNT + sizeof(unsigned) * N_NODES, stream);

    detect_k<<<4, 256, 0, stream>>>(ei, flag);
    count_k<<<(N_EDGES + 255) / 256, 256, 0, stream>>>(ei, flag, cnt);
    scanA_k<<<N_CHUNKS, 256, 0, stream>>>(cnt, tot);
    scanB_k<<<1, 64, 0, stream>>>(tot);
    scanC_k<<<N_CHUNKS, 256, 0, stream>>>(cnt, tot, offs, cur);
    fill_k<<<(N_EDGES + 255) / 256, 256, 0, stream>>>(ei, flag, cur, col);

    f2b_k<<<(N_NODES * DIM / 4 + 255) / 256, 256, 0, stream>>>(x, xbf, N_NODES * DIM / 4);
    wconv_k<<<dim3(DIM * DIM / 4 / 256, 4), 256, 0, stream>>>(Wl0, Wr0, Wl1, Wr1,
                                                              wl0b, wr0b, wl1b, wr1b);

    // layer 0: xbf -> h1
    agg_k<<<(N_NODES + 15) / 16, 256, 0, stream>>>(xbf, offs, cnt, col, aggm);
    xform_mfma_k<true><<<(N_NODES + 63) / 64, 256, 0, stream>>>(aggm, xbf, wl0b, wr0b, b0, h1);
    // layer 1: h1 -> h2
    agg_k<<<(N_NODES + 15) / 16, 256, 0, stream>>>(h1, offs, cnt, col, aggm);
    xform_mfma_k<true><<<(N_NODES + 63) / 64, 256, 0, stream>>>(aggm, h1, wl1b, wr1b, b1, h2);
    // layer 2: h2 -> out
    agg_k<<<(N_NODES + 15) / 16, 256, 0, stream>>>(h2, offs, cnt, col, aggm);
    out2_k<<<(N_NODES + 255) / 256, 256, 0, stream>>>(aggm, h2, Wl2, Wr2, b2, out);
}

// Round 4
// 223.972 us; speedup vs baseline: 2.0183x; 1.2373x over previous
//
#include <hip/hip_runtime.h>
#include <hip/hip_bf16.h>

#define N_NODES 50000
#define N_EDGES 600000
#define DIM 128

#define SCAN_CHUNK 2048
#define N_CHUNKS ((N_NODES + SCAN_CHUNK - 1) / SCAN_CHUNK)   // 25

typedef short bf16x8 __attribute__((ext_vector_type(8)));
typedef float f32x4 __attribute__((ext_vector_type(4)));

__device__ __forceinline__ ushort f2b(float f) {
    __hip_bfloat16 h = __float2bfloat16(f);
    return *reinterpret_cast<ushort*>(&h);
}
__device__ __forceinline__ float b2f_lo(unsigned u) { return __uint_as_float(u << 16); }
__device__ __forceinline__ float b2f_hi(unsigned u) { return __uint_as_float(u & 0xffff0000u); }

static constexpr size_t alignup(size_t x) { return (x + 255) & ~size_t(255); }
static constexpr size_t OFF_FLAG = 0;
static constexpr size_t OFF_TOT  = 256;
static constexpr size_t OFF_CNT  = alignup(OFF_TOT + sizeof(unsigned) * N_CHUNKS);
static constexpr size_t OFF_OFFS = alignup(OFF_CNT + sizeof(unsigned) * N_NODES);
static constexpr size_t OFF_CUR  = alignup(OFF_OFFS + sizeof(unsigned) * (N_NODES + 1));
static constexpr size_t OFF_COL  = alignup(OFF_CUR + sizeof(unsigned) * N_NODES);
static constexpr size_t OFF_XBF  = alignup(OFF_COL + sizeof(int) * N_EDGES);
static constexpr size_t OFF_AGG  = alignup(OFF_XBF + sizeof(ushort) * N_NODES * DIM);
static constexpr size_t OFF_H1   = alignup(OFF_AGG + sizeof(ushort) * N_NODES * DIM);
static constexpr size_t OFF_H2   = alignup(OFF_H1 + sizeof(ushort) * N_NODES * DIM);
static constexpr size_t OFF_WL0  = alignup(OFF_H2 + sizeof(ushort) * N_NODES * DIM);
static constexpr size_t OFF_WR0  = alignup(OFF_WL0 + sizeof(ushort) * DIM * DIM);
static constexpr size_t OFF_WL1  = alignup(OFF_WR0 + sizeof(ushort) * DIM * DIM);
static constexpr size_t OFF_WR1  = alignup(OFF_WL1 + sizeof(ushort) * DIM * DIM);

// ---- workspace zero (replaces hipMemsetAsync / rocclr fillBuffer) ----
__global__ __launch_bounds__(256) void zero_k(unsigned* __restrict__ flag,
                                              unsigned* __restrict__ tot,
                                              unsigned* __restrict__ cnt) {
    int i = blockIdx.x * 256 + threadIdx.x;
    if (i < N_NODES) cnt[i] = 0u;
    if (i < N_CHUNKS) tot[i] = 0u;
    if (i == 0) *flag = 0u;
}

// ---- edge dtype detection: int64 arrays have zero high words at odd indices ----
__global__ void detect_k(const int* __restrict__ ei, unsigned* __restrict__ flag) {
    int g = blockIdx.x * blockDim.x + threadIdx.x;
    if (g < 1024) {
        unsigned v = (unsigned)ei[2 * g + 1];
        if (v) atomicOr(flag, 1u);   // nonzero odd word => int32 layout
    }
}

// flag != 0 : int32 layout; flag == 0 : int64 layout. 4 edges per thread.
__global__ void count_k(const int* __restrict__ ei, const unsigned* __restrict__ flag,
                        unsigned* __restrict__ cnt) {
    int e0 = (blockIdx.x * 256 + threadIdx.x) * 4;
    if (e0 >= N_EDGES) return;
    if (*flag) {
        uint4 d = *reinterpret_cast<const uint4*>(&ei[N_EDGES + e0]);
        atomicAdd(&cnt[d.x], 1u); atomicAdd(&cnt[d.y], 1u);
        atomicAdd(&cnt[d.z], 1u); atomicAdd(&cnt[d.w], 1u);
    } else {
        uint4 a = *reinterpret_cast<const uint4*>(&ei[2 * (N_EDGES + e0)]);
        uint4 b = *reinterpret_cast<const uint4*>(&ei[2 * (N_EDGES + e0) + 4]);
        atomicAdd(&cnt[a.x], 1u); atomicAdd(&cnt[a.z], 1u);
        atomicAdd(&cnt[b.x], 1u); atomicAdd(&cnt[b.z], 1u);
    }
}

// ---- 3-phase chunked exclusive scan ----
__global__ __launch_bounds__(256) void scanA_k(const unsigned* __restrict__ cnt,
                                               unsigned* __restrict__ totals) {
    __shared__ unsigned red[256];
    const int b = blockIdx.x, t = threadIdx.x;
    const int base = b * SCAN_CHUNK + t * 8;
    unsigned s = 0;
#pragma unroll
    for (int i = 0; i < 8; ++i) {
        int idx = base + i;
        if (idx < N_NODES) s += cnt[idx];
    }
    red[t] = s;
    __syncthreads();
    for (int d = 128; d > 0; d >>= 1) {
        if (t < d) red[t] += red[t + d];
        __syncthreads();
    }
    if (t == 0) totals[b] = red[0];
}

__global__ void scanB_k(unsigned* __restrict__ totals) {   // 64 threads
    int t = threadIdx.x;
    unsigned orig = (t < N_CHUNKS) ? totals[t] : 0u;
    unsigned v = orig;
    for (int d = 1; d < 64; d <<= 1) {
        unsigned n = __shfl_up(v, d);
        if (t >= d) v += n;
    }
    if (t < N_CHUNKS) totals[t] = v - orig;   // exclusive
}

__global__ __launch_bounds__(256) void scanC_k(const unsigned* __restrict__ cnt,
                                               const unsigned* __restrict__ totals,
                                               unsigned* __restrict__ offs,
                                               unsigned* __restrict__ cur) {
    __shared__ unsigned tsum[256];
    const int b = blockIdx.x, t = threadIdx.x;
    const int base = b * SCAN_CHUNK + t * 8;
    unsigned v[8];
    unsigned s = 0;
#pragma unroll
    for (int i = 0; i < 8; ++i) {
        int idx = base + i;
        v[i] = (idx < N_NODES) ? cnt[idx] : 0u;
        s += v[i];
    }
    tsum[t] = s;
    __syncthreads();
    for (int d = 1; d < 256; d <<= 1) {
        unsigned nv = (t >= d) ? tsum[t - d] : 0u;
        __syncthreads();
        tsum[t] += nv;
        __syncthreads();
    }
    unsigned run = tsum[t] - s + totals[b];
    for (int i = 0; i < 8; ++i) {
        int idx = base + i;
        if (idx < N_NODES) {
            offs[idx] = run;
            cur[idx]  = run;
            run += v[i];
            if (idx == N_NODES - 1) offs[N_NODES] = run;
        }
    }
}

__global__ void fill_k(const int* __restrict__ ei, const unsigned* __restrict__ flag,
                       unsigned* __restrict__ cur, int* __restrict__ col) {
    int e0 = (blockIdx.x * 256 + threadIdx.x) * 4;
    if (e0 >= N_EDGES) return;
    int s[4], d[4];
    if (*flag) {
        uint4 sv = *reinterpret_cast<const uint4*>(&ei[e0]);
        uint4 dv = *reinterpret_cast<const uint4*>(&ei[N_EDGES + e0]);
        s[0] = sv.x; s[1] = sv.y; s[2] = sv.z; s[3] = sv.w;
        d[0] = dv.x; d[1] = dv.y; d[2] = dv.z; d[3] = dv.w;
    } else {
        uint4 sa = *reinterpret_cast<const uint4*>(&ei[2 * e0]);
        uint4 sb = *reinterpret_cast<const uint4*>(&ei[2 * e0 + 4]);
        uint4 da = *reinterpret_cast<const uint4*>(&ei[2 * (N_EDGES + e0)]);
        uint4 db = *reinterpret_cast<const uint4*>(&ei[2 * (N_EDGES + e0) + 4]);
        s[0] = sa.x; s[1] = sa.z; s[2] = sb.x; s[3] = sb.z;
        d[0] = da.x; d[1] = da.z; d[2] = db.x; d[3] = db.z;
    }
#pragma unroll
    for (int i = 0; i < 4; ++i) {
        unsigned pos = atomicAdd(&cur[d[i]], 1u);
        col[pos] = s[i];
    }
}

// ---- f32 -> bf16 converters ----
__global__ __launch_bounds__(256) void f2b_k(const float* __restrict__ src,
                                             ushort* __restrict__ dst, int n4) {
    int i = blockIdx.x * 256 + threadIdx.x;
    if (i >= n4) return;
    float4 v = reinterpret_cast<const float4*>(src)[i];
    ushort4 o;
    o.x = f2b(v.x); o.y = f2b(v.y); o.z = f2b(v.z); o.w = f2b(v.w);
    reinterpret_cast<ushort4*>(dst)[i] = o;
}

__global__ __launch_bounds__(256) void wconv_k(const float* __restrict__ a, const float* __restrict__ b,
                                               const float* __restrict__ c, const float* __restrict__ d,
                                               ushort* __restrict__ oa, ushort* __restrict__ ob,
                                               ushort* __restrict__ oc, ushort* __restrict__ od) {
    const int w = blockIdx.y;
    const float* src = (w == 0) ? a : (w == 1) ? b : (w == 2) ? c : d;
    ushort* dst      = (w == 0) ? oa : (w == 1) ? ob : (w == 2) ? oc : od;
    int i = blockIdx.x * 256 + threadIdx.x;          // DIM*DIM/4 = 4096 threads
    float4 v = reinterpret_cast<const float4*>(src)[i];
    ushort4 o;
    o.x = f2b(v.x); o.y = f2b(v.y); o.z = f2b(v.z); o.w = f2b(v.w);
    reinterpret_cast<ushort4*>(dst)[i] = o;
}

// ---- mean-aggregate (bf16 in, f32 accum, bf16 out): 16 nodes/block, 16 lanes/node ----
__global__ __launch_bounds__(256) void agg_k(const ushort* __restrict__ h,
                                             const unsigned* __restrict__ offs,
                                             const int* __restrict__ col,
                                             ushort* __restrict__ aggm) {
    int g    = threadIdx.x >> 4;
    int lane = threadIdx.x & 15;
    int node = blockIdx.x * 16 + g;
    if (node >= N_NODES) return;
    unsigned e0 = offs[node], e1 = offs[node + 1];
    float acc[8];
#pragma unroll
    for (int i = 0; i < 8; ++i) acc[i] = 0.f;
    for (unsigned e = e0; e < e1; ++e) {
        int s = col[e];
        uint4 v = *reinterpret_cast<const uint4*>(&h[(size_t)s * DIM + lane * 8]);
        acc[0] += b2f_lo(v.x); acc[1] += b2f_hi(v.x);
        acc[2] += b2f_lo(v.y); acc[3] += b2f_hi(v.y);
        acc[4] += b2f_lo(v.z); acc[5] += b2f_hi(v.z);
        acc[6] += b2f_lo(v.w); acc[7] += b2f_hi(v.w);
    }
    float inv = 1.0f / fmaxf((float)(e1 - e0), 1.0f);
    uint4 o;
    o.x = (unsigned)f2b(acc[0] * inv) | ((unsigned)f2b(acc[1] * inv) << 16);
    o.y = (unsigned)f2b(acc[2] * inv) | ((unsigned)f2b(acc[3] * inv) << 16);
    o.z = (unsigned)f2b(acc[4] * inv) | ((unsigned)f2b(acc[5] * inv) << 16);
    o.w = (unsigned)f2b(acc[6] * inv) | ((unsigned)f2b(acc[7] * inv) << 16);
    *reinterpret_cast<uint4*>(&aggm[(size_t)node * DIM + lane * 8]) = o;
}

// ---- hout = [relu]( aggm @ Wl^T + b + hin @ Wr^T ) via bf16 MFMA, W staged in LDS ----
// Per block: 64 nodes, 4 waves (16 nodes each). Two phases (Wl then Wr); each phase
// cooperatively stages W [128][128] bf16 into LDS padded [128][136] (row stride 272 B:
// rows land 16 B apart mod 128 B -> ds_read_b128 at the capacity floor, no conflict tax).
template <bool RELU>
__global__ __launch_bounds__(256) void xform_mfma_k(const ushort* __restrict__ A0,   // aggm
                                                    const ushort* __restrict__ A1,   // hin (root)
                                                    const ushort* __restrict__ Wl,
                                                    const ushort* __restrict__ Wr,
                                                    const float*  __restrict__ bias,
                                                    ushort* __restrict__ hout) {
    __shared__ ushort Ws[128 * 136];                     // 34816 B
    const int t    = threadIdx.x;
    const int wave = t >> 6;
    const int l    = t & 63;
    const int l16  = l & 15;
    const int lk   = (l >> 4) * 8;                       // k offset within 32-chunk
    const int node = blockIdx.x * 64 + wave * 16 + l16;
    const bool valid = node < N_NODES;

    const int wrow = t >> 1;                             // W staging: row 0..127
    const int wc0  = (t & 1) * 64;                       // 64 ushorts per thread

    f32x4 acc[8];
#pragma unroll
    for (int i = 0; i < 8; ++i) acc[i] = (f32x4){0.f, 0.f, 0.f, 0.f};

    const bf16x8 zfrag = (bf16x8){0, 0, 0, 0, 0, 0, 0, 0};

#pragma unroll
    for (int p = 0; p < 2; ++p) {
        const ushort* Asrc = p ? A1 : A0;
        const ushort* Wsrc = p ? Wr : Wl;

        // issue node-feature loads early (independent of LDS)
        bf16x8 bf[4];
#pragma unroll
        for (int ks = 0; ks < 4; ++ks)
            bf[ks] = valid
                ? *reinterpret_cast<const bf16x8*>(&Asrc[(size_t)node * DIM + ks * 32 + lk])
                : zfrag;

        __syncthreads();                                  // prior-phase LDS reads done
        {   // stage W: 256 threads x 128 B (8 x uint4), coalesced
            const uint4* src = reinterpret_cast<const uint4*>(&Wsrc[(size_t)wrow * DIM + wc0]);
            uint4* dst = reinterpret_cast<uint4*>(&Ws[wrow * 136 + wc0]);
#pragma unroll
            for (int i = 0; i < 8; ++i) dst[i] = src[i];
        }
        __syncthreads();

#pragma unroll
        for (int ks = 0; ks < 4; ++ks) {
            const int kb = ks * 32;
#pragma unroll
            for (int ot = 0; ot < 8; ++ot) {
                const bf16x8 afrag = *reinterpret_cast<const bf16x8*>(
                    &Ws[(ot * 16 + l16) * 136 + kb + lk]);
                acc[ot] = __builtin_amdgcn_mfma_f32_16x16x32_bf16(afrag, bf[ks], acc[ot], 0, 0, 0);
            }
        }
    }

    if (!valid) return;
    const int orow = (l >> 4) * 4;
#pragma unroll
    for (int ot = 0; ot < 8; ++ot) {
        const float4 b4 = *reinterpret_cast<const float4*>(&bias[ot * 16 + orow]);
        float r0 = acc[ot][0] + b4.x;
        float r1 = acc[ot][1] + b4.y;
        float r2 = acc[ot][2] + b4.z;
        float r3 = acc[ot][3] + b4.w;
        if (RELU) {
            r0 = fmaxf(r0, 0.f); r1 = fmaxf(r1, 0.f);
            r2 = fmaxf(r2, 0.f); r3 = fmaxf(r3, 0.f);
        }
        ushort4 s;
        s.x = f2b(r0); s.y = f2b(r1); s.z = f2b(r2); s.w = f2b(r3);
        *reinterpret_cast<ushort4*>(&hout[(size_t)node * DIM + ot * 16 + orow]) = s;
    }
}

// ---- final layer fused: mean-aggregate h2 + 2-dim linear, f32 throughout ----
__global__ __launch_bounds__(256) void out2_fused_k(const ushort* __restrict__ h,
                                                    const unsigned* __restrict__ offs,
                                                    const int* __restrict__ col,
                                                    const float* __restrict__ Wl,
                                                    const float* __restrict__ Wr,
                                                    const float* __restrict__ bias,
                                                    float* __restrict__ out) {
    __shared__ float wl[256], wr[256];                    // [o*128 + k]
    const int t = threadIdx.x;
    wl[t] = Wl[t];
    wr[t] = Wr[t];
    __syncthreads();
    const int g = t >> 4, lane = t & 15;
    const int node = blockIdx.x * 16 + g;
    if (node >= N_NODES) return;
    const unsigned e0 = offs[node], e1 = offs[node + 1];
    float acc[8];
#pragma unroll
    for (int i = 0; i < 8; ++i) acc[i] = 0.f;
    for (unsigned e = e0; e < e1; ++e) {
        int s = col[e];
        uint4 v = *reinterpret_cast<const uint4*>(&h[(size_t)s * DIM + lane * 8]);
        acc[0] += b2f_lo(v.x); acc[1] += b2f_hi(v.x);
        acc[2] += b2f_lo(v.y); acc[3] += b2f_hi(v.y);
        acc[4] += b2f_lo(v.z); acc[5] += b2f_hi(v.z);
        acc[6] += b2f_lo(v.w); acc[7] += b2f_hi(v.w);
    }
    const float inv = 1.0f / fmaxf((float)(e1 - e0), 1.0f);
    const uint4 rv = *reinterpret_cast<const uint4*>(&h[(size_t)node * DIM + lane * 8]);
    float root[8];
    root[0] = b2f_lo(rv.x); root[1] = b2f_hi(rv.x);
    root[2] = b2f_lo(rv.y); root[3] = b2f_hi(rv.y);
    root[4] = b2f_lo(rv.z); root[5] = b2f_hi(rv.z);
    root[6] = b2f_lo(rv.w); root[7] = b2f_hi(rv.w);
    const int kb = lane * 8;
    float p0 = 0.f, p1 = 0.f;
#pragma unroll
    for (int j = 0; j < 8; ++j) {
        const float av = acc[j] * inv;
        p0 += av * wl[kb + j] + root[j] * wr[kb + j];
        p1 += av * wl[128 + kb + j] + root[j] * wr[128 + kb + j];
    }
#pragma unroll
    for (int m = 1; m < 16; m <<= 1) {
        p0 += __shfl_xor(p0, m);
        p1 += __shfl_xor(p1, m);
    }
    if (lane == 0) {
        out[(size_t)node * 2 + 0] = p0 + bias[0];
        out[(size_t)node * 2 + 1] = p1 + bias[1];
    }
}

extern "C" void kernel_launch(void* const* d_in, const int* in_sizes, int n_in,
                              void* d_out, int out_size, void* d_ws, size_t ws_size,
                              hipStream_t stream) {
    const float* x   = (const float*)d_in[0];
    const int*   ei  = (const int*)d_in[1];
    const float* Wl0 = (const float*)d_in[2];
    const float* Wr0 = (const float*)d_in[3];
    const float* b0  = (const float*)d_in[4];
    const float* Wl1 = (const float*)d_in[5];
    const float* Wr1 = (const float*)d_in[6];
    const float* b1  = (const float*)d_in[7];
    const float* Wl2 = (const float*)d_in[8];
    const float* Wr2 = (const float*)d_in[9];
    const float* b2  = (const float*)d_in[10];

    char* ws = (char*)d_ws;
    unsigned* flag = (unsigned*)(ws + OFF_FLAG);
    unsigned* tot  = (unsigned*)(ws + OFF_TOT);
    unsigned* cnt  = (unsigned*)(ws + OFF_CNT);
    unsigned* offs = (unsigned*)(ws + OFF_OFFS);
    unsigned* cur  = (unsigned*)(ws + OFF_CUR);
    int*      col  = (int*)(ws + OFF_COL);
    ushort*   xbf  = (ushort*)(ws + OFF_XBF);
    ushort*   aggm = (ushort*)(ws + OFF_AGG);
    ushort*   h1   = (ushort*)(ws + OFF_H1);
    ushort*   h2   = (ushort*)(ws + OFF_H2);
    ushort*   wl0b = (ushort*)(ws + OFF_WL0);
    ushort*   wr0b = (ushort*)(ws + OFF_WR0);
    ushort*   wl1b = (ushort*)(ws + OFF_WL1);
    ushort*   wr1b = (ushort*)(ws + OFF_WR1);
    float*    out  = (float*)d_out;

    zero_k<<<(N_NODES + 255) / 256, 256, 0, stream>>>(flag, tot, cnt);
    detect_k<<<4, 256, 0, stream>>>(ei, flag);
    count_k<<<(N_EDGES / 4 + 255) / 256, 256, 0, stream>>>(ei, flag, cnt);
    scanA_k<<<N_CHUNKS, 256, 0, stream>>>(cnt, tot);
    scanB_k<<<1, 64, 0, stream>>>(tot);
    scanC_k<<<N_CHUNKS, 256, 0, stream>>>(cnt, tot, offs, cur);
    fill_k<<<(N_EDGES / 4 + 255) / 256, 256, 0, stream>>>(ei, flag, cur, col);

    f2b_k<<<(N_NODES * DIM / 4 + 255) / 256, 256, 0, stream>>>(x, xbf, N_NODES * DIM / 4);
    wconv_k<<<dim3(DIM * DIM / 4 / 256, 4), 256, 0, stream>>>(Wl0, Wr0, Wl1, Wr1,
                                                              wl0b, wr0b, wl1b, wr1b);

    // layer 0: xbf -> h1
    agg_k<<<(N_NODES + 15) / 16, 256, 0, stream>>>(xbf, offs, col, aggm);
    xform_mfma_k<true><<<(N_NODES + 63) / 64, 256, 0, stream>>>(aggm, xbf, wl0b, wr0b, b0, h1);
    // layer 1: h1 -> h2
    agg_k<<<(N_NODES + 15) / 16, 256, 0, stream>>>(h1, offs, col, aggm);
    xform_mfma_k<true><<<(N_NODES + 63) / 64, 256, 0, stream>>>(aggm, h1, wl1b, wr1b, b1, h2);
    // layer 2 fused: aggregate h2 + linear -> out
    out2_fused_k<<<(N_NODES + 15) / 16, 256, 0, stream>>>(h2, offs, col, Wl2, Wr2, b2, out);
}